// Round 17
// baseline (355.786 us; speedup 1.0000x reference)
//
#include <hip/hip_runtime.h>
#include <hip/hip_bf16.h>
#include <stdint.h>

static constexpr int ND = 8192;

typedef __attribute__((ext_vector_type(8))) short bf16x8;
typedef __attribute__((ext_vector_type(4))) float f32x4;

#define GLOBAL_AS __attribute__((address_space(1)))
#define LDS_AS __attribute__((address_space(3)))

__device__ __forceinline__ void gld_lds16(const void* g, void* l) {
    __builtin_amdgcn_global_load_lds((const GLOBAL_AS void*)g, (LDS_AS void*)l, 16, 0, 0);
}

__device__ __forceinline__ unsigned short f2bf(float x) {
    union { float f; uint32_t u; } v; v.f = x;
    uint32_t u = v.u;
    uint32_t r = (u + 0x7fffu + ((u >> 16) & 1u)) >> 16;
    return (unsigned short)r;
}

// ---------------- pre-pass 1: Aw[i][k] = (k>=i) ? bf16(A[i][k]) : 0 ----------------
__global__ void conv_a(const float* __restrict__ A, unsigned short* __restrict__ Aw) {
    uint32_t g = blockIdx.x * 256u + threadIdx.x;
    int i  = (int)(g >> 10);
    int k0 = (int)(g & 1023u) << 3;
    if (k0 + 8 <= (i & ~255)) return;          // never read: k < (i>>8)*256
    const float* src = A + (size_t)i * ND + k0;
    f32x4 lo = __builtin_nontemporal_load((const f32x4*)src);
    f32x4 hi = __builtin_nontemporal_load((const f32x4*)(src + 4));
    float vals[8] = {lo[0], lo[1], lo[2], lo[3], hi[0], hi[1], hi[2], hi[3]};
    unsigned short out[8];
#pragma unroll
    for (int e = 0; e < 8; ++e) {
        int k = k0 + e;
        out[e] = (k >= i) ? f2bf(vals[e]) : (unsigned short)0;
    }
    *(uint4*)(Aw + (size_t)i * ND + k0) = *(const uint4*)out;
}

// ------------- pre-pass 2: Bt[j][k] = (k<=j) ? bf16(B[k][j]) : 0 (transpose) -------------
__global__ void conv_bt(const float* __restrict__ B, unsigned short* __restrict__ Bt) {
    __shared__ float tile[64][65];
    int tk = blockIdx.x, tj = blockIdx.y;
    int t = threadIdx.x;
    int k0 = tk * 64, j0 = tj * 64;

    if (k0 > j0 + 63) {                         // tile wholly above diagonal (k > j)
        if (tk >= ((tj >> 2) + 1) * 4) return;  // beyond the 256-block: never read
        int jl = t >> 4;
        int kl = (t & 15) * 4;
#pragma unroll
        for (int r = 0; r < 4; ++r) {
            int j = j0 + jl + r * 16;
            *(uint2*)(Bt + (size_t)j * ND + k0 + kl) = make_uint2(0u, 0u);
        }
        return;
    }
    {   // load: coalesced in j, nontemporal (read-once)
        int kl  = t >> 4;
        int jl4 = (t & 15) * 4;
#pragma unroll
        for (int r = 0; r < 4; ++r) {
            int k = k0 + kl + r * 16;
            f32x4 v = __builtin_nontemporal_load(
                (const f32x4*)(B + (size_t)k * ND + j0 + jl4));
            tile[kl + r * 16][jl4 + 0] = v[0];
            tile[kl + r * 16][jl4 + 1] = v[1];
            tile[kl + r * 16][jl4 + 2] = v[2];
            tile[kl + r * 16][jl4 + 3] = v[3];
        }
    }
    __syncthreads();
    {   // store: coalesced in k (cacheable — re-read by gemm)
        int jl  = t >> 4;
        int kl4 = (t & 15) * 4;
#pragma unroll
        for (int r = 0; r < 4; ++r) {
            int j = j0 + jl + r * 16;
            unsigned short o[4];
#pragma unroll
            for (int e = 0; e < 4; ++e) {
                int k = k0 + kl4 + e;
                float v = tile[kl4 + e][jl + r * 16];
                o[e] = (k <= j) ? f2bf(v) : (unsigned short)0;
            }
            *(uint2*)(Bt + (size_t)j * ND + k0 + kl4) = *(const uint2*)o;
        }
    }
}

// ===== main GEMM: 256x256 tiles, 8-phase pipeline, COLUMN-MAJOR quad order =====
// Super-columns J=15..0 (descending). Column 15 touches EVERY A row-panel over its
// full k-range -> all 69 MB of A is HBM-fetched exactly once; every later column's
// A reads are L3 hits (A upper-tri = 69 MB resident). B panels stream ~2 cols per
// column-step. Window working set ~140 MB < 256 MB L3 (quad-LPT's was ~300 MB ->
// churn -> 4x re-fetch). Kernel body identical to R14 (verified).
// + fused mirror-tile zeroing in the epilogue (every C element written once).
#define BAR() __builtin_amdgcn_s_barrier()
#define WAIT_LGKM0() asm volatile("s_waitcnt lgkmcnt(0)" ::: "memory")
#define WAIT_VM4() asm volatile("s_waitcnt vmcnt(4)" ::: "memory")
#define WAIT_VM0() asm volatile("s_waitcnt vmcnt(0)" ::: "memory")
#define PRIO(x) __builtin_amdgcn_s_setprio(x)

#define LDA(BUF, MH) do { \
    _Pragma("unroll") for (int m_ = 0; m_ < 4; ++m_) \
    _Pragma("unroll") for (int kk_ = 0; kk_ < 2; ++kk_) \
        a_frag[m_][kk_] = *(const bf16x8*)(lds0 + (((BUF)*2 + 0)*2 + (MH))*8192 \
            + (a_lr + m_*16)*64 + (((kk_*4 + khi) ^ lanelo) << 3)); \
} while (0)

#define LDB(BUF, NH) do { \
    _Pragma("unroll") for (int n_ = 0; n_ < 2; ++n_) \
    _Pragma("unroll") for (int kk_ = 0; kk_ < 2; ++kk_) \
        b_frag[NH][n_][kk_] = *(const bf16x8*)(lds0 + (((BUF)*2 + 1)*2 + (NH))*8192 \
            + (b_lr + n_*16)*64 + (((kk_*4 + khi) ^ lanelo) << 3)); \
} while (0)

#define MM(MH, NH) do { \
    _Pragma("unroll") for (int kk_ = 0; kk_ < 2; ++kk_) \
    _Pragma("unroll") for (int m_ = 0; m_ < 4; ++m_) \
    _Pragma("unroll") for (int n_ = 0; n_ < 2; ++n_) \
        acc[(MH)*4 + m_][(NH)*2 + n_] = __builtin_amdgcn_mfma_f32_16x16x32_bf16( \
            a_frag[m_][kk_], b_frag[NH][n_][kk_], acc[(MH)*4 + m_][(NH)*2 + n_], 0, 0, 0); \
} while (0)

// Column J holds: 4*J off-diagonal quad members (q=0..J-1, longest-q first since
// q asc = longer K) then 3 diagonal members of super-tile (J,J). 528 jobs total.
__device__ __forceinline__ void job_map_col(int bid, int& tib, int& tjb) {
    int rem = bid;
#pragma unroll 1
    for (int J = 15; J >= 0; --J) {
        int nj = 4 * J + 3;
        if (rem < nj) {
            if (rem < 4 * J) {                   // off-diagonal quad member
                int q = rem >> 2, r = rem & 3;
                tib = 2 * q + (r >> 1);
                tjb = 2 * J + (r & 1);
            } else {                             // diagonal super-tile (J,J): 3 members
                int r = rem - 4 * J;
                tib = 2 * J + (r >> 1);          // r=0,1 -> 2J ; r=2 -> 2J+1
                tjb = 2 * J + (r ? 1 : 0);       // r=0 -> 2J ; r=1,2 -> 2J+1
            }
            return;
        }
        rem -= nj;
    }
    tib = 0; tjb = 0;                            // unreachable
}

__global__ __launch_bounds__(512, 2) void gemm_tri8(const unsigned short* __restrict__ Aw,
                                                    const unsigned short* __restrict__ Bt,
                                                    float* __restrict__ C) {
    int tib, tjb;
    job_map_col(blockIdx.x, tib, tjb);

    __shared__ __align__(16) unsigned short lds[2][2][2][128][64];
    unsigned short* lds0 = &lds[0][0][0][0][0];

    int t = threadIdx.x;
    int lane = t & 63, w = t >> 6;
    int wr = w >> 2, wc = w & 3;
    int lanelo = lane & 7, khi = lane >> 4;
    int a_lr = wr * 64 + (lane & 15);
    int b_lr = wc * 32 + (lane & 15);

    int kstart = tib * 256;
    int nkt = (tjb - tib + 1) * 4;
    int nit = nkt >> 1;

    int srow = w * 8 + (lane >> 3);
    int sg = ((lane & 7) ^ (lane >> 3)) * 8;
    const unsigned short* gA = Aw + (size_t)(tib * 256 + srow) * ND + sg;
    const unsigned short* gB = Bt + (size_t)(tjb * 256 + srow) * ND + sg;
    unsigned short* sdst = lds0 + (w * 512 + lane * 8);

    auto STAGE = [&](int ab, int buf, int h, int ktg) {
        const unsigned short* g = (ab ? gB : gA) + (size_t)(h * 128) * ND + (kstart + ktg * 64);
        unsigned short* l = sdst + ((buf * 2 + ab) * 2 + h) * 8192;
        gld_lds16(g, l);
        gld_lds16(g + (size_t)64 * ND, l + 4096);
    };

    f32x4 acc[8][4];
#pragma unroll
    for (int m = 0; m < 8; ++m)
#pragma unroll
        for (int n = 0; n < 4; ++n) acc[m][n] = (f32x4){0.f, 0.f, 0.f, 0.f};

    bf16x8 a_frag[4][2];
    bf16x8 b_frag[2][2][2];

    // prologue: kt0 fully + kt1 A0,B0 (leave kt1's 2 half-tiles in flight)
    STAGE(0, 0, 0, 0); STAGE(1, 0, 0, 0); STAGE(0, 0, 1, 0); STAGE(1, 0, 1, 0);
    STAGE(0, 1, 0, 1); STAGE(1, 1, 0, 1);
    WAIT_VM4();
    BAR();

    for (int I = 0; I < nit; ++I) {
        int k1 = 2 * I + 1, k2 = 2 * I + 2, k3 = 2 * I + 3;
        bool s23 = (k2 < nkt);

        LDA(0, 0); LDB(0, 0);
        STAGE(0, 1, 1, k1);
        BAR(); WAIT_LGKM0(); PRIO(1); MM(0, 0); PRIO(0); BAR();
        LDB(0, 1);
        STAGE(1, 1, 1, k1);
        BAR(); WAIT_LGKM0(); PRIO(1); MM(0, 1); PRIO(0); BAR();
        LDA(0, 1);
        if (s23) STAGE(0, 0, 0, k2);
        BAR(); WAIT_LGKM0(); PRIO(1); MM(1, 0); PRIO(0); BAR();
        if (s23) STAGE(1, 0, 0, k2);
        BAR(); PRIO(1); MM(1, 1); PRIO(0);
        if (s23) { WAIT_VM4(); } else { WAIT_VM0(); }
        BAR();
        LDA(1, 0); LDB(1, 0);
        if (s23) STAGE(0, 0, 1, k2);
        BAR(); WAIT_LGKM0(); PRIO(1); MM(0, 0); PRIO(0); BAR();
        LDB(1, 1);
        if (s23) STAGE(1, 0, 1, k2);
        BAR(); WAIT_LGKM0(); PRIO(1); MM(0, 1); PRIO(0); BAR();
        LDA(1, 1);
        if (s23) STAGE(0, 1, 0, k3);
        BAR(); WAIT_LGKM0(); PRIO(1); MM(1, 0); PRIO(0); BAR();
        if (s23) STAGE(1, 1, 0, k3);
        BAR(); PRIO(1); MM(1, 1); PRIO(0); WAIT_VM4(); BAR();
    }

    // epilogue 1: C/D layout col=lane&15, row=(lane>>4)*4+e — nontemporal stores
#pragma unroll
    for (int mh = 0; mh < 2; ++mh)
#pragma unroll
        for (int m = 0; m < 4; ++m)
#pragma unroll
            for (int nh = 0; nh < 2; ++nh)
#pragma unroll
                for (int n = 0; n < 2; ++n) {
                    f32x4 v = acc[mh * 4 + m][nh * 2 + n];
                    int row0 = tib * 256 + mh * 128 + wr * 64 + m * 16 + (lane >> 4) * 4;
                    int col  = tjb * 256 + nh * 128 + wc * 32 + n * 16 + (lane & 15);
#pragma unroll
                    for (int e = 0; e < 4; ++e)
                        __builtin_nontemporal_store(
                            v[e], &C[(size_t)(row0 + e) * ND + col]);
                }

    // epilogue 2: zero the MIRROR (strictly-lower) 256x256 tile (off-diagonal only)
    if (tib != tjb) {
        float* zb = C + (size_t)(tjb * 256) * ND + tib * 256;
        f32x4 z = {0.f, 0.f, 0.f, 0.f};
#pragma unroll
        for (int it = 0; it < 32; ++it) {
            int row = it * 8 + w;
            __builtin_nontemporal_store(z, (f32x4*)(zb + (size_t)row * ND + lane * 4));
        }
    }
}

// ---------------- fallback (only if ws too small): slow but correct ----------------
__global__ void tri_naive(const float* __restrict__ A, const float* __restrict__ B,
                          float* __restrict__ C) {
    int j = blockIdx.x * 64 + (threadIdx.x & 63);
    int i = blockIdx.y * 4 + (threadIdx.x >> 6);
    float s = 0.f;
    if (j >= i) {
        for (int k = i; k <= j; ++k) s += A[(size_t)i * ND + k] * B[(size_t)k * ND + j];
        C[(size_t)i * ND + j] = s;
    } else {
        C[(size_t)i * ND + j] = 0.f;
    }
}

extern "C" void kernel_launch(void* const* d_in, const int* in_sizes, int n_in,
                              void* d_out, int out_size, void* d_ws, size_t ws_size,
                              hipStream_t stream) {
    (void)in_sizes; (void)n_in; (void)out_size;
    const float* A = (const float*)d_in[0];
    const float* B = (const float*)d_in[1];
    float* C = (float*)d_out;

    const size_t halfws = (size_t)ND * ND * sizeof(unsigned short);  // 128 MiB
    if (ws_size >= 2 * halfws) {
        unsigned short* Aw = (unsigned short*)d_ws;
        unsigned short* Bt = (unsigned short*)((char*)d_ws + halfws);

        conv_a<<<dim3(ND * (ND / 8) / 256), dim3(256), 0, stream>>>(A, Aw);
        conv_bt<<<dim3(ND / 64, ND / 64), dim3(256), 0, stream>>>(B, Bt);
        // lower-triangle zeroing is fused into gemm_tri8's epilogue (mirror tiles)
        gemm_tri8<<<dim3(528), dim3(512), 0, stream>>>(Aw, Bt, C);
    } else {
        tri_naive<<<dim3(ND / 64, ND / 4), dim3(256), 0, stream>>>(A, B, C);
    }
}

// Round 18
// 311.135 us; speedup vs baseline: 1.1435x; 1.1435x over previous
//
#include <hip/hip_runtime.h>
#include <hip/hip_bf16.h>
#include <stdint.h>

static constexpr int ND = 8192;

typedef __attribute__((ext_vector_type(8))) short bf16x8;
typedef __attribute__((ext_vector_type(4))) float f32x4;

#define GLOBAL_AS __attribute__((address_space(1)))
#define LDS_AS __attribute__((address_space(3)))

__device__ __forceinline__ void gld_lds16(const void* g, void* l) {
    __builtin_amdgcn_global_load_lds((const GLOBAL_AS void*)g, (LDS_AS void*)l, 16, 0, 0);
}

__device__ __forceinline__ unsigned short f2bf(float x) {
    union { float f; uint32_t u; } v; v.f = x;
    uint32_t u = v.u;
    uint32_t r = (u + 0x7fffu + ((u >> 16) & 1u)) >> 16;
    return (unsigned short)r;
}

// ---------------- pre-pass 1: Aw[i][k] = (k>=i) ? bf16(A[i][k]) : 0 ----------------
__global__ void conv_a(const float* __restrict__ A, unsigned short* __restrict__ Aw) {
    uint32_t g = blockIdx.x * 256u + threadIdx.x;
    int i  = (int)(g >> 10);
    int k0 = (int)(g & 1023u) << 3;
    if (k0 + 8 <= (i & ~255)) return;          // never read: k < (i>>8)*256
    const float* src = A + (size_t)i * ND + k0;
    f32x4 lo = __builtin_nontemporal_load((const f32x4*)src);
    f32x4 hi = __builtin_nontemporal_load((const f32x4*)(src + 4));
    float vals[8] = {lo[0], lo[1], lo[2], lo[3], hi[0], hi[1], hi[2], hi[3]};
    unsigned short out[8];
#pragma unroll
    for (int e = 0; e < 8; ++e) {
        int k = k0 + e;
        out[e] = (k >= i) ? f2bf(vals[e]) : (unsigned short)0;
    }
    *(uint4*)(Aw + (size_t)i * ND + k0) = *(const uint4*)out;
}

// ------------- pre-pass 2: Bt[j][k] = (k<=j) ? bf16(B[k][j]) : 0 (transpose) -------------
__global__ void conv_bt(const float* __restrict__ B, unsigned short* __restrict__ Bt) {
    __shared__ float tile[64][65];
    int tk = blockIdx.x, tj = blockIdx.y;
    int t = threadIdx.x;
    int k0 = tk * 64, j0 = tj * 64;

    if (k0 > j0 + 63) {                         // tile wholly above diagonal (k > j)
        if (tk >= ((tj >> 2) + 1) * 4) return;  // beyond the 256-block: never read
        int jl = t >> 4;
        int kl = (t & 15) * 4;
#pragma unroll
        for (int r = 0; r < 4; ++r) {
            int j = j0 + jl + r * 16;
            *(uint2*)(Bt + (size_t)j * ND + k0 + kl) = make_uint2(0u, 0u);
        }
        return;
    }
    {   // load: coalesced in j, nontemporal (read-once)
        int kl  = t >> 4;
        int jl4 = (t & 15) * 4;
#pragma unroll
        for (int r = 0; r < 4; ++r) {
            int k = k0 + kl + r * 16;
            f32x4 v = __builtin_nontemporal_load(
                (const f32x4*)(B + (size_t)k * ND + j0 + jl4));
            tile[kl + r * 16][jl4 + 0] = v[0];
            tile[kl + r * 16][jl4 + 1] = v[1];
            tile[kl + r * 16][jl4 + 2] = v[2];
            tile[kl + r * 16][jl4 + 3] = v[3];
        }
    }
    __syncthreads();
    {   // store: coalesced in k (cacheable — re-read by gemm)
        int jl  = t >> 4;
        int kl4 = (t & 15) * 4;
#pragma unroll
        for (int r = 0; r < 4; ++r) {
            int j = j0 + jl + r * 16;
            unsigned short o[4];
#pragma unroll
            for (int e = 0; e < 4; ++e) {
                int k = k0 + kl4 + e;
                float v = tile[kl4 + e][jl + r * 16];
                o[e] = (k <= j) ? f2bf(v) : (unsigned short)0;
            }
            *(uint2*)(Bt + (size_t)j * ND + k0 + kl4) = *(const uint2*)o;
        }
    }
}

// ===== main GEMM: 256x256 tiles, 8-phase pipeline, QUAD-clustered LPT (final) =====
// Best measured configuration (R14/R16: 311.7-312.4 us total, gemm ~235 us):
// - 2x2 quad clustering, super-diagonal descending (adjacent-bid panel sharing
//   was the only job-order lever that improved FETCH AND time; 4x4 regressed)
// - 8-phase schedule, counted vmcnt(4) (deeper pipeline measured neutral)
// - XOR-swizzled LDS via pre-swizzled global source (bank conflicts = 0)
// - fused mirror-tile zeroing in epilogue (replaces separate zero pass, -14 us)
// - nontemporal C stores; absmax 2.0 (bf16 MFMA, threshold 8.96)
#define BAR() __builtin_amdgcn_s_barrier()
#define WAIT_LGKM0() asm volatile("s_waitcnt lgkmcnt(0)" ::: "memory")
#define WAIT_VM4() asm volatile("s_waitcnt vmcnt(4)" ::: "memory")
#define WAIT_VM0() asm volatile("s_waitcnt vmcnt(0)" ::: "memory")
#define PRIO(x) __builtin_amdgcn_s_setprio(x)

#define LDA(BUF, MH) do { \
    _Pragma("unroll") for (int m_ = 0; m_ < 4; ++m_) \
    _Pragma("unroll") for (int kk_ = 0; kk_ < 2; ++kk_) \
        a_frag[m_][kk_] = *(const bf16x8*)(lds0 + (((BUF)*2 + 0)*2 + (MH))*8192 \
            + (a_lr + m_*16)*64 + (((kk_*4 + khi) ^ lanelo) << 3)); \
} while (0)

#define LDB(BUF, NH) do { \
    _Pragma("unroll") for (int n_ = 0; n_ < 2; ++n_) \
    _Pragma("unroll") for (int kk_ = 0; kk_ < 2; ++kk_) \
        b_frag[NH][n_][kk_] = *(const bf16x8*)(lds0 + (((BUF)*2 + 1)*2 + (NH))*8192 \
            + (b_lr + n_*16)*64 + (((kk_*4 + khi) ^ lanelo) << 3)); \
} while (0)

#define MM(MH, NH) do { \
    _Pragma("unroll") for (int kk_ = 0; kk_ < 2; ++kk_) \
    _Pragma("unroll") for (int m_ = 0; m_ < 4; ++m_) \
    _Pragma("unroll") for (int n_ = 0; n_ < 2; ++n_) \
        acc[(MH)*4 + m_][(NH)*2 + n_] = __builtin_amdgcn_mfma_f32_16x16x32_bf16( \
            a_frag[m_][kk_], b_frag[NH][n_][kk_], acc[(MH)*4 + m_][(NH)*2 + n_], 0, 0, 0); \
} while (0)

__device__ __forceinline__ void job_map_quad(int bid, int& tib, int& tjb) {
    int rem = bid;
#pragma unroll 1
    for (int sd = 15; sd >= 1; --sd) {           // super-diagonal desc (LPT)
        int jobs = 4 * (16 - sd);
        if (rem < jobs) {
            int q = rem >> 2, r = rem & 3;
            tib = 2 * q + (r >> 1);
            tjb = 2 * (q + sd) + (r & 1);
            return;
        }
        rem -= jobs;
    }
    // sd == 0: diagonal super-tiles, 3 valid tiles each
    int si = rem / 3, r = rem - si * 3;
    tib = 2 * si + (r >> 1);                     // r=0,1 -> 2si ; r=2 -> 2si+1
    tjb = 2 * si + (r ? 1 : 0);                  // r=0 -> 2si ; r=1,2 -> 2si+1
}

__global__ __launch_bounds__(512, 2) void gemm_tri8(const unsigned short* __restrict__ Aw,
                                                    const unsigned short* __restrict__ Bt,
                                                    float* __restrict__ C) {
    int tib, tjb;
    job_map_quad(blockIdx.x, tib, tjb);

    __shared__ __align__(16) unsigned short lds[2][2][2][128][64];
    unsigned short* lds0 = &lds[0][0][0][0][0];

    int t = threadIdx.x;
    int lane = t & 63, w = t >> 6;
    int wr = w >> 2, wc = w & 3;
    int lanelo = lane & 7, khi = lane >> 4;
    int a_lr = wr * 64 + (lane & 15);
    int b_lr = wc * 32 + (lane & 15);

    int kstart = tib * 256;
    int nkt = (tjb - tib + 1) * 4;
    int nit = nkt >> 1;

    int srow = w * 8 + (lane >> 3);
    int sg = ((lane & 7) ^ (lane >> 3)) * 8;
    const unsigned short* gA = Aw + (size_t)(tib * 256 + srow) * ND + sg;
    const unsigned short* gB = Bt + (size_t)(tjb * 256 + srow) * ND + sg;
    unsigned short* sdst = lds0 + (w * 512 + lane * 8);

    auto STAGE = [&](int ab, int buf, int h, int ktg) {
        const unsigned short* g = (ab ? gB : gA) + (size_t)(h * 128) * ND + (kstart + ktg * 64);
        unsigned short* l = sdst + ((buf * 2 + ab) * 2 + h) * 8192;
        gld_lds16(g, l);
        gld_lds16(g + (size_t)64 * ND, l + 4096);
    };

    f32x4 acc[8][4];
#pragma unroll
    for (int m = 0; m < 8; ++m)
#pragma unroll
        for (int n = 0; n < 4; ++n) acc[m][n] = (f32x4){0.f, 0.f, 0.f, 0.f};

    bf16x8 a_frag[4][2];
    bf16x8 b_frag[2][2][2];

    // prologue: kt0 fully + kt1 A0,B0 (leave kt1's 2 half-tiles in flight)
    STAGE(0, 0, 0, 0); STAGE(1, 0, 0, 0); STAGE(0, 0, 1, 0); STAGE(1, 0, 1, 0);
    STAGE(0, 1, 0, 1); STAGE(1, 1, 0, 1);
    WAIT_VM4();
    BAR();

    for (int I = 0; I < nit; ++I) {
        int k1 = 2 * I + 1, k2 = 2 * I + 2, k3 = 2 * I + 3;
        bool s23 = (k2 < nkt);

        LDA(0, 0); LDB(0, 0);
        STAGE(0, 1, 1, k1);
        BAR(); WAIT_LGKM0(); PRIO(1); MM(0, 0); PRIO(0); BAR();
        LDB(0, 1);
        STAGE(1, 1, 1, k1);
        BAR(); WAIT_LGKM0(); PRIO(1); MM(0, 1); PRIO(0); BAR();
        LDA(0, 1);
        if (s23) STAGE(0, 0, 0, k2);
        BAR(); WAIT_LGKM0(); PRIO(1); MM(1, 0); PRIO(0); BAR();
        if (s23) STAGE(1, 0, 0, k2);
        BAR(); PRIO(1); MM(1, 1); PRIO(0);
        if (s23) { WAIT_VM4(); } else { WAIT_VM0(); }
        BAR();
        LDA(1, 0); LDB(1, 0);
        if (s23) STAGE(0, 0, 1, k2);
        BAR(); WAIT_LGKM0(); PRIO(1); MM(0, 0); PRIO(0); BAR();
        LDB(1, 1);
        if (s23) STAGE(1, 0, 1, k2);
        BAR(); WAIT_LGKM0(); PRIO(1); MM(0, 1); PRIO(0); BAR();
        LDA(1, 1);
        if (s23) STAGE(0, 1, 0, k3);
        BAR(); WAIT_LGKM0(); PRIO(1); MM(1, 0); PRIO(0); BAR();
        if (s23) STAGE(1, 1, 0, k3);
        BAR(); PRIO(1); MM(1, 1); PRIO(0); WAIT_VM4(); BAR();
    }

    // epilogue 1: C/D layout col=lane&15, row=(lane>>4)*4+e — nontemporal stores
#pragma unroll
    for (int mh = 0; mh < 2; ++mh)
#pragma unroll
        for (int m = 0; m < 4; ++m)
#pragma unroll
            for (int nh = 0; nh < 2; ++nh)
#pragma unroll
                for (int n = 0; n < 2; ++n) {
                    f32x4 v = acc[mh * 4 + m][nh * 2 + n];
                    int row0 = tib * 256 + mh * 128 + wr * 64 + m * 16 + (lane >> 4) * 4;
                    int col  = tjb * 256 + nh * 128 + wc * 32 + n * 16 + (lane & 15);
#pragma unroll
                    for (int e = 0; e < 4; ++e)
                        __builtin_nontemporal_store(
                            v[e], &C[(size_t)(row0 + e) * ND + col]);
                }

    // epilogue 2: zero the MIRROR (strictly-lower) 256x256 tile (off-diagonal only).
    // wave w writes row it*8 + w, lanes cover 256 cols (1 KiB/wave) — coalesced.
    if (tib != tjb) {
        float* zb = C + (size_t)(tjb * 256) * ND + tib * 256;
        f32x4 z = {0.f, 0.f, 0.f, 0.f};
#pragma unroll
        for (int it = 0; it < 32; ++it) {
            int row = it * 8 + w;
            __builtin_nontemporal_store(z, (f32x4*)(zb + (size_t)row * ND + lane * 4));
        }
    }
}

// ---------------- fallback (only if ws too small): slow but correct ----------------
__global__ void tri_naive(const float* __restrict__ A, const float* __restrict__ B,
                          float* __restrict__ C) {
    int j = blockIdx.x * 64 + (threadIdx.x & 63);
    int i = blockIdx.y * 4 + (threadIdx.x >> 6);
    float s = 0.f;
    if (j >= i) {
        for (int k = i; k <= j; ++k) s += A[(size_t)i * ND + k] * B[(size_t)k * ND + j];
        C[(size_t)i * ND + j] = s;
    } else {
        C[(size_t)i * ND + j] = 0.f;
    }
}

extern "C" void kernel_launch(void* const* d_in, const int* in_sizes, int n_in,
                              void* d_out, int out_size, void* d_ws, size_t ws_size,
                              hipStream_t stream) {
    (void)in_sizes; (void)n_in; (void)out_size;
    const float* A = (const float*)d_in[0];
    const float* B = (const float*)d_in[1];
    float* C = (float*)d_out;

    const size_t halfws = (size_t)ND * ND * sizeof(unsigned short);  // 128 MiB
    if (ws_size >= 2 * halfws) {
        unsigned short* Aw = (unsigned short*)d_ws;
        unsigned short* Bt = (unsigned short*)((char*)d_ws + halfws);

        conv_a<<<dim3(ND * (ND / 8) / 256), dim3(256), 0, stream>>>(A, Aw);
        conv_bt<<<dim3(ND / 64, ND / 64), dim3(256), 0, stream>>>(B, Bt);
        // lower-triangle zeroing is fused into gemm_tri8's epilogue (mirror tiles)
        gemm_tri8<<<dim3(528), dim3(512), 0, stream>>>(Aw, Bt, C);
    } else {
        tri_naive<<<dim3(ND / 64, ND / 4), dim3(256), 0, stream>>>(A, B, C);
    }
}